// Round 12
// baseline (258.330 us; speedup 1.0000x reference)
//
#include <hip/hip_runtime.h>
#include <hip/hip_bf16.h>

#define DEV __device__ __forceinline__

typedef unsigned short u16;
typedef __attribute__((ext_vector_type(8))) short bf16x8;
typedef __attribute__((ext_vector_type(4))) float f32x4;
typedef __attribute__((ext_vector_type(16))) float f32x16;
typedef __attribute__((ext_vector_type(4))) unsigned short us4;
typedef __attribute__((ext_vector_type(2))) unsigned u32x2;

DEV void gld_lds16(const void* g, void* l) {
  __builtin_amdgcn_global_load_lds((const __attribute__((address_space(1))) void*)g,
                                   (__attribute__((address_space(3))) void*)l, 16, 0, 0);
}

DEV u16 f2bf(float x) {  // RNE f32->bf16 (inputs finite)
  union { float f; unsigned u; } v; v.f = x;
  unsigned r = v.u + 0x7FFFu + ((v.u >> 16) & 1u);
  return (u16)(r >> 16);
}

DEV float ex2(float x) {  // 2^x
  float r; asm("v_exp_f32 %0, %1" : "=v"(r) : "v"(x)); return r;
}

DEV unsigned cvtpk(float a, float b) {  // [bf16(b)<<16 | bf16(a)]
  unsigned r; asm("v_cvt_pk_bf16_f32 %0, %1, %2" : "=v"(r) : "v"(a), "v"(b)); return r;
}

// ---------------- prep: cast x to bf16 ----------------
__global__ __launch_bounds__(256) void k_cast_x(const float* __restrict__ x, u16* __restrict__ xb) {
  int i = (blockIdx.x * 256 + threadIdx.x) * 4;
  const float4 v = *(const float4*)(x + i);
  us4 o; o.x = f2bf(v.x); o.y = f2bf(v.y); o.z = f2bf(v.z); o.w = f2bf(v.w);
  *(us4*)(xb + i) = o;
}

// ---------------- prep: transpose-pack weights to bf16 ----------------
// Wq/Wk/Wv: [H][1024][64] -> wqkvt rows {0,1024,2048}+ (h*64+d), cols m ; Wo -> wot[n][m]
__global__ __launch_bounds__(256) void k_prep_w(const float* __restrict__ Wq, const float* __restrict__ Wk,
                                                const float* __restrict__ Wv, const float* __restrict__ Wo,
                                                u16* __restrict__ wqkvt, u16* __restrict__ wot) {
  __shared__ float t[64][65];
  const int bb = blockIdx.x, tid = threadIdx.x;
  const float* src; u16* dst; int src_ld, dst_row0, dst_col0;
  if (bb < 768) {
    int which = bb >> 8, h = (bb >> 4) & 15, m0 = (bb & 15) * 64;
    const float* W = which == 0 ? Wq : (which == 1 ? Wk : Wv);
    src = W + h * 65536 + m0 * 64; src_ld = 64;
    dst = wqkvt + which * (1024 * 1024);
    dst_row0 = h * 64; dst_col0 = m0;
  } else {
    int t2 = bb - 768, mt = t2 >> 4, nt = t2 & 15;
    src = Wo + (size_t)(mt * 64) * 1024 + nt * 64; src_ld = 1024;
    dst = wot; dst_row0 = nt * 64; dst_col0 = mt * 64;
  }
  {
    int r = tid >> 2, c0 = (tid & 3) * 16;
    const float* s = src + (size_t)r * src_ld + c0;
#pragma unroll
    for (int q = 0; q < 4; ++q) {
      float4 v = *(const float4*)(s + q * 4);
      t[r][c0 + q * 4 + 0] = v.x; t[r][c0 + q * 4 + 1] = v.y;
      t[r][c0 + q * 4 + 2] = v.z; t[r][c0 + q * 4 + 3] = v.w;
    }
  }
  __syncthreads();
  {
    int d = tid >> 2, mb = (tid & 3) * 16;
    bf16x8 v0, v1;
#pragma unroll
    for (int e = 0; e < 8; ++e) {
      v0[e] = (short)f2bf(t[mb + e][d]);
      v1[e] = (short)f2bf(t[mb + 8 + e][d]);
    }
    u16* dp = dst + (size_t)(dst_row0 + d) * 1024 + dst_col0 + mb;
    *(bf16x8*)(dp) = v0;
    *(bf16x8*)(dp + 8) = v1;
  }
}

// ---------------- GEMM: C[M,N] = A[M,K] x Bt[N,K]^T (+bias, epilogue by MODE) ----------------
// ROUND-11 VERIFIED, byte-identical: BK=32, 2 buffers (32KB -> 4 blocks/CU), vmcnt(0)+barrier
// per K-step, XCD supertile mapping. Bit-identical accumulation order vs BK=64.
// MODE 0: flat 768 blocks; each XCD owns an 8bm x 12bn chunk. Bt=[Wq|Wk|Wv]^T.
//         j<1024: Q*scale -> qk ; 1024<=j<2048: K -> qk ; j>=2048: V -> vt transposed.
// MODE 2: flat 256 blocks; bn = XCD. out f32 d_out[4096,1024] (+bo)
template <int MODE>
__global__ __launch_bounds__(256) void k_gemm(const u16* __restrict__ A, const u16* __restrict__ Bt,
                                              const float* __restrict__ b0, const float* __restrict__ b1,
                                              const float* __restrict__ b2,
                                              u16* __restrict__ outb, u16* __restrict__ outv,
                                              float* __restrict__ outf) {
  constexpr int K = 1024;
  constexpr int NT = 32;  // K-tiles of BK=32
  __shared__ __align__(16) u16 As[2][128 * 32];
  __shared__ __align__(16) u16 Bs[2][128 * 32];
  const int tid = threadIdx.x, wid = tid >> 6, lane = tid & 63;
  const int lo = lane & 15, hi = lane >> 4;
  const int wr = wid >> 1, wc = wid & 1;
  int bm, bn;
  if (MODE == 0) {  // 768 blocks: blockIdx&7 = XCD owns an 8x12 (bm,bn) chunk (bijective)
    const int xcd = blockIdx.x & 7, s = blockIdx.x >> 3;
    bm = (xcd & 3) * 8 + (s & 7);
    bn = (xcd >> 2) * 12 + (s >> 3);
  } else {          // 256 blocks: bn = XCD (one B panel per XCD), bm streams
    bn = blockIdx.x & 7; bm = blockIdx.x >> 3;
  }
  const u16* Ab = A + (size_t)bm * 128 * K;
  const u16* Bb = Bt + (size_t)bn * 128 * K;

  // staging geometry (per wave, 2 instrs each for A and B)
  const int c0 = (wid * 2 + 0) * 64 + lane;   // chunk ids
  const int c1 = c0 + 64;
  const int row0 = c0 >> 2, row1 = c1 >> 2;
  const int g0 = (c0 & 3) ^ ((row0 >> 1) & 3);  // pre-swizzled source k-chunk
  const int g1 = (c1 & 3) ^ ((row1 >> 1) & 3);
  const u16* a_src0 = Ab + (size_t)row0 * K + g0 * 8;
  const u16* a_src1 = Ab + (size_t)row1 * K + g1 * 8;
  const u16* b_src0 = Bb + (size_t)row0 * K + g0 * 8;
  const u16* b_src1 = Bb + (size_t)row1 * K + g1 * 8;
  const int ld0 = (wid * 2 + 0) * 512;  // wave-uniform LDS u16 base (lane*16B implicit)
  const int ld1 = (wid * 2 + 1) * 512;

#define GSTAGE(T, BF)                          \
  {                                            \
    const int kk = (T) * 32;                   \
    gld_lds16(a_src0 + kk, &As[BF][ld0]);      \
    gld_lds16(a_src1 + kk, &As[BF][ld1]);      \
    gld_lds16(b_src0 + kk, &Bs[BF][ld0]);      \
    gld_lds16(b_src1 + kk, &Bs[BF][ld1]);      \
  }

  f32x4 acc[4][4] = {};
  const int fslot = (hi ^ ((lo >> 1) & 3)) * 8;  // frag read slot (2-way free)

  GSTAGE(0, 0)
  int cur = 0;
#pragma unroll 1
  for (int t = 0; t < NT; ++t) {
    asm volatile("s_waitcnt vmcnt(0)" ::: "memory");
    __builtin_amdgcn_s_barrier();
    if (t + 1 < NT) GSTAGE(t + 1, cur ^ 1)
    {
      bf16x8 af[4], bfr[4];
#pragma unroll
      for (int mt = 0; mt < 4; ++mt)
        af[mt] = *(const bf16x8*)(&As[cur][(wr * 64 + mt * 16 + lo) * 32 + fslot]);
#pragma unroll
      for (int nt = 0; nt < 4; ++nt)
        bfr[nt] = *(const bf16x8*)(&Bs[cur][(wc * 64 + nt * 16 + lo) * 32 + fslot]);
#pragma unroll
      for (int mt = 0; mt < 4; ++mt)
#pragma unroll
        for (int nt = 0; nt < 4; ++nt)
          acc[mt][nt] = __builtin_amdgcn_mfma_f32_16x16x32_bf16(af[mt], bfr[nt], acc[mt][nt], 0, 0, 0);
    }
    cur ^= 1;
  }
#undef GSTAGE

#pragma unroll
  for (int mt = 0; mt < 4; ++mt) {
#pragma unroll
    for (int nt = 0; nt < 4; ++nt) {
      const int i0 = bm * 128 + wr * 64 + mt * 16 + hi * 4;
      const int j = bn * 128 + wc * 64 + nt * 16 + lo;
      if (MODE == 0) {
        if (j < 2048) {
#pragma unroll
          for (int rg = 0; rg < 4; ++rg) {
            float v = acc[mt][nt][rg];
            v += (j < 1024) ? b0[j] : b1[j - 1024];
            if (j < 1024) v *= 0.18033688011112042f;  // (1/8)*log2(e): exp2-domain logits
            outb[(size_t)(i0 + rg) * 2048 + j] = f2bf(v);
          }
        } else {  // V: transpose-store, 4 consecutive t packed
          const float bb2 = b2[j - 2048];
          uint2 w;
          w.x = cvtpk(acc[mt][nt][0] + bb2, acc[mt][nt][1] + bb2);
          w.y = cvtpk(acc[mt][nt][2] + bb2, acc[mt][nt][3] + bb2);
          *(uint2*)(outv + (size_t)((i0 >> 11) * 1024 + (j - 2048)) * 2048 + (i0 & 2047)) = w;
        }
      } else {
#pragma unroll
        for (int rg = 0; rg < 4; ++rg)
          outf[(size_t)(i0 + rg) * 1024 + j] = acc[mt][nt][rg] + b0[j];
      }
    }
  }
}

// ---------------- flash attention (32x32 MFMA, in-register P, FIXED-m softmax) ----------------
// Round-10 T15 schedule with 3 K/V buffers (48KB LDS -> 3 blocks/CU, was 2).
// Ledger: PRE(T) = vmcnt(0) BEFORE barrier (each wave drains its own stage loads, barrier
// publishes all waves' -> cross-wave safe), then STAGE(T+2) into buf (T+2)%3 = tile T-1's
// buffer (its reads completed before this barrier). Live tiles: T (SMPV), T+1 (QK), T+2
// (staging) = 3. Barriers are asm volatile with memory clobber (pin compiler ordering).
__global__ __launch_bounds__(256, 3) void k_attn(const u16* __restrict__ qk, const u16* __restrict__ vt,
                                                 u16* __restrict__ ao) {
  __shared__ __align__(16) u16 Kl0[3 * 4096];
  __shared__ __align__(16) u16 Vl0[3 * 4096];
  const int tid = threadIdx.x, wid = tid >> 6, lane = tid & 63;
  const int ql = lane & 31, Lh = lane >> 5;
  const int logical = (blockIdx.x & 7) * 64 + (blockIdx.x >> 3);  // bijective (512 = 8*64)
  const int qb = logical & 15, bh = logical >> 4;
  const int b = bh >> 4, h = bh & 15;
  const int qg = qb * 128 + wid * 32 + ql;

  // Q as B-frags (lane: n=q=ql, k=d), kd=0..3
  bf16x8 qB[4];
  const u16* qrow = qk + (size_t)(b * 2048 + qg) * 2048 + h * 64;
#pragma unroll
  for (int kd = 0; kd < 4; ++kd) qB[kd] = *(const bf16x8*)(qrow + kd * 16 + Lh * 8);

  const u16* Kg = qk + 1024 + (size_t)b * 2048 * 2048 + h * 64;  // + t*2048
  const u16* Vg = vt + (size_t)bh * 64 * 2048;                   // + d*2048 + t
  const int sr = lane >> 3, sc = lane & 7;

  f32x16 acco[2] = {};
  float l_part = 0.f;
  f32x16 sA0, sA1, sB0, sB1;

#define STAGE(T)                                                                        \
  {                                                                                     \
    const int sb_ = (T) % 3, t0_ = (T) * 64;                                            \
    _Pragma("unroll") for (int i = 0; i < 2; ++i) {                                     \
      int r = wid * 16 + i * 8 + sr;                                                    \
      int cs = sc ^ (r & 7);                                                            \
      gld_lds16(Kg + (size_t)(t0_ + r) * 2048 + cs * 8, Kl0 + sb_ * 4096 + (wid * 16 + i * 8) * 64); \
      gld_lds16(Vg + (size_t)r * 2048 + t0_ + cs * 8, Vl0 + sb_ * 4096 + (wid * 16 + i * 8) * 64);   \
    }                                                                                   \
  }

#define PRE(T)                                                                          \
  {                                                                                     \
    asm volatile("s_waitcnt vmcnt(0)" ::: "memory");                                    \
    asm volatile("s_barrier" ::: "memory");                                             \
    if ((T) + 2 < 32) STAGE((T) + 2)                                                    \
  }

#define QK(S0, S1, T)                                                                   \
  {                                                                                     \
    const u16* Kb = Kl0 + ((T) % 3) * 4096;                                             \
    S0 = (f32x16){}; S1 = (f32x16){};                                                   \
    bf16x8 ka0[4], ka1[4];                                                              \
    _Pragma("unroll") for (int kd = 0; kd < 4; ++kd) {                                  \
      const int cg = 2 * kd + Lh;                                                       \
      const int r0 = ql, r1 = 32 + ql;                                                  \
      ka0[kd] = *(const bf16x8*)(Kb + r0 * 64 + ((cg ^ (r0 & 7)) * 8));                 \
      ka1[kd] = *(const bf16x8*)(Kb + r1 * 64 + ((cg ^ (r1 & 7)) * 8));                 \
    }                                                                                   \
    __builtin_amdgcn_s_setprio(1);                                                      \
    _Pragma("unroll") for (int kd = 0; kd < 4; ++kd) {                                  \
      S0 = __builtin_amdgcn_mfma_f32_32x32x16_bf16(ka0[kd], qB[kd], S0, 0, 0, 0);       \
      S1 = __builtin_amdgcn_mfma_f32_32x32x16_bf16(ka1[kd], qB[kd], S1, 0, 0, 0);       \
    }                                                                                   \
    __builtin_amdgcn_s_setprio(0);                                                      \
  }

#define SMPV(S0, S1, T)                                                                 \
  {                                                                                     \
    const u16* Vb = Vl0 + ((T) % 3) * 4096;                                             \
    bf16x8 vf[2][4];                                                                    \
    _Pragma("unroll") for (int dt = 0; dt < 2; ++dt) _Pragma("unroll")                  \
        for (int kt = 0; kt < 4; ++kt) {                                                \
          int r = dt * 32 + ql;                                                         \
          int cg = 2 * kt + Lh;                                                         \
          vf[dt][kt] = *(const bf16x8*)(Vb + r * 64 + ((cg ^ (r & 7)) * 8));            \
        }                                                                               \
    unsigned dw0[8], dw1[8];                                                            \
    float ls0 = 0.f, ls1 = 0.f;                                                         \
    _Pragma("unroll") for (int m = 0; m < 8; ++m) {                                     \
      float p0 = ex2(S0[2 * m]), p1 = ex2(S0[2 * m + 1]);                               \
      float p2 = ex2(S1[2 * m]), p3 = ex2(S1[2 * m + 1]);                               \
      ls0 += p0 + p1; ls1 += p2 + p3;                                                   \
      dw0[m] = cvtpk(p0, p1); dw1[m] = cvtpk(p2, p3);                                   \
    }                                                                                   \
    l_part += ls0 + ls1;                                                                \
    __builtin_amdgcn_s_setprio(1);                                                      \
    _Pragma("unroll") for (int kt = 0; kt < 4; ++kt) {                                  \
      const int c = kt & 1;                                                             \
      unsigned w0, w1, w2, w3;                                                          \
      if (kt < 2) { w0 = dw0[4 * c + 0]; w1 = dw0[4 * c + 2];                           \
                    w2 = dw0[4 * c + 1]; w3 = dw0[4 * c + 3]; }                         \
      else        { w0 = dw1[4 * c + 0]; w1 = dw1[4 * c + 2];                           \
                    w2 = dw1[4 * c + 1]; w3 = dw1[4 * c + 3]; }                         \
      u32x2 s0 = __builtin_amdgcn_permlane32_swap(w0, w1, false, false);                \
      u32x2 s1 = __builtin_amdgcn_permlane32_swap(w2, w3, false, false);                \
      union { unsigned u[4]; bf16x8 v; } pb;                                            \
      pb.u[0] = s0[0]; pb.u[1] = s1[0]; pb.u[2] = s0[1]; pb.u[3] = s1[1];               \
      acco[0] = __builtin_amdgcn_mfma_f32_32x32x16_bf16(vf[0][kt], pb.v, acco[0], 0, 0, 0); \
      acco[1] = __builtin_amdgcn_mfma_f32_32x32x16_bf16(vf[1][kt], pb.v, acco[1], 0, 0, 0); \
    }                                                                                   \
    __builtin_amdgcn_s_setprio(0);                                                      \
  }

  // prologue: stage tiles 0,1 ; drain tile0 (cross-wave via barrier) ; QK(0) -> A
  STAGE(0) STAGE(1)
  asm volatile("s_waitcnt vmcnt(4)" ::: "memory");
  asm volatile("s_barrier" ::: "memory");
  QK(sA0, sA1, 0)

#pragma unroll 1
  for (int it = 0; it < 32; it += 2) {
    PRE(it)                     // drains tile it+1; stages tile it+2 into buf (it+2)%3
    QK(sB0, sB1, it + 1)
    SMPV(sA0, sA1, it)
    PRE(it + 1)                 // drains tile it+2; stages tile it+3
    if (it + 2 < 32) QK(sA0, sA1, it + 2)
    SMPV(sB0, sB1, it + 1)
  }
#undef STAGE
#undef PRE
#undef QK
#undef SMPV

  // epilogue: O[q][d], d = 32dt + 8g + 4Lh + (reg&3)
  float lsum = l_part + __shfl_xor(l_part, 32);
  float inv = 1.f / lsum;
  u16* orow = ao + (size_t)(b * 2048 + qg) * 1024 + h * 64;
#pragma unroll
  for (int dt = 0; dt < 2; ++dt)
#pragma unroll
    for (int g = 0; g < 4; ++g) {
      float o0 = acco[dt][4 * g + 0] * inv, o1 = acco[dt][4 * g + 1] * inv;
      float o2 = acco[dt][4 * g + 2] * inv, o3 = acco[dt][4 * g + 3] * inv;
      uint2 w; w.x = cvtpk(o0, o1); w.y = cvtpk(o2, o3);
      *(uint2*)(orow + dt * 32 + g * 8 + Lh * 4) = w;
    }
}

// ---------------- launch ----------------
extern "C" void kernel_launch(void* const* d_in, const int* in_sizes, int n_in,
                              void* d_out, int out_size, void* d_ws, size_t ws_size,
                              hipStream_t stream) {
  const float* x  = (const float*)d_in[0];
  const float* Wq = (const float*)d_in[1];
  const float* bq = (const float*)d_in[2];
  const float* Wk = (const float*)d_in[3];
  const float* bk = (const float*)d_in[4];
  const float* Wv = (const float*)d_in[5];
  const float* bv = (const float*)d_in[6];
  const float* Wo = (const float*)d_in[7];
  const float* bo = (const float*)d_in[8];
  float* out = (float*)d_out;

  char* ws = (char*)d_ws;
  u16* xb    = (u16*)(ws);                       // 8 MB  x bf16 [4096][1024]
  u16* wqkvt = (u16*)(ws + (8u << 20));          // 6 MB  [3072][1024]
  u16* wot   = (u16*)(ws + (14u << 20));         // 2 MB  [1024][1024]
  u16* qk    = (u16*)(ws + (16u << 20));         // 16 MB [4096][2048]
  u16* vt    = (u16*)(ws + (32u << 20));         // 8 MB  [2*16*64][2048]
  u16* aob   = (u16*)(ws + (40u << 20));         // 8 MB  [4096][1024]   (48 MB total)

  k_cast_x<<<4096, 256, 0, stream>>>(x, xb);
  k_prep_w<<<1024, 256, 0, stream>>>(Wq, Wk, Wv, Wo, wqkvt, wot);
  k_gemm<0><<<768, 256, 0, stream>>>(xb, wqkvt, bq, bk, bv, qk, vt, nullptr);
  k_attn<<<512, 256, 0, stream>>>(qk, vt, aob);
  k_gemm<2><<<256, 256, 0, stream>>>(aob, wot, bo, nullptr, nullptr, nullptr, nullptr, out);
}

// Round 13
// 115.114 us; speedup vs baseline: 2.2441x; 2.2441x over previous
//
#include <hip/hip_runtime.h>
#include <hip/hip_bf16.h>

#define DEV __device__ __forceinline__

typedef unsigned short u16;
typedef __attribute__((ext_vector_type(8))) short bf16x8;
typedef __attribute__((ext_vector_type(4))) float f32x4;
typedef __attribute__((ext_vector_type(16))) float f32x16;
typedef __attribute__((ext_vector_type(4))) unsigned short us4;
typedef __attribute__((ext_vector_type(2))) unsigned u32x2;

DEV void gld_lds16(const void* g, void* l) {
  __builtin_amdgcn_global_load_lds((const __attribute__((address_space(1))) void*)g,
                                   (__attribute__((address_space(3))) void*)l, 16, 0, 0);
}

DEV u16 f2bf(float x) {  // RNE f32->bf16 (inputs finite)
  union { float f; unsigned u; } v; v.f = x;
  unsigned r = v.u + 0x7FFFu + ((v.u >> 16) & 1u);
  return (u16)(r >> 16);
}

DEV float ex2(float x) {  // 2^x
  float r; asm("v_exp_f32 %0, %1" : "=v"(r) : "v"(x)); return r;
}

DEV unsigned cvtpk(float a, float b) {  // [bf16(b)<<16 | bf16(a)]
  unsigned r; asm("v_cvt_pk_bf16_f32 %0, %1, %2" : "=v"(r) : "v"(a), "v"(b)); return r;
}

// ---------------- prep: cast x to bf16 ----------------
__global__ __launch_bounds__(256) void k_cast_x(const float* __restrict__ x, u16* __restrict__ xb) {
  int i = (blockIdx.x * 256 + threadIdx.x) * 4;
  const float4 v = *(const float4*)(x + i);
  us4 o; o.x = f2bf(v.x); o.y = f2bf(v.y); o.z = f2bf(v.z); o.w = f2bf(v.w);
  *(us4*)(xb + i) = o;
}

// ---------------- prep: transpose-pack weights to bf16 ----------------
// Wq/Wk/Wv: [H][1024][64] -> wqkvt rows {0,1024,2048}+ (h*64+d), cols m ; Wo -> wot[n][m]
__global__ __launch_bounds__(256) void k_prep_w(const float* __restrict__ Wq, const float* __restrict__ Wk,
                                                const float* __restrict__ Wv, const float* __restrict__ Wo,
                                                u16* __restrict__ wqkvt, u16* __restrict__ wot) {
  __shared__ float t[64][65];
  const int bb = blockIdx.x, tid = threadIdx.x;
  const float* src; u16* dst; int src_ld, dst_row0, dst_col0;
  if (bb < 768) {
    int which = bb >> 8, h = (bb >> 4) & 15, m0 = (bb & 15) * 64;
    const float* W = which == 0 ? Wq : (which == 1 ? Wk : Wv);
    src = W + h * 65536 + m0 * 64; src_ld = 64;
    dst = wqkvt + which * (1024 * 1024);
    dst_row0 = h * 64; dst_col0 = m0;
  } else {
    int t2 = bb - 768, mt = t2 >> 4, nt = t2 & 15;
    src = Wo + (size_t)(mt * 64) * 1024 + nt * 64; src_ld = 1024;
    dst = wot; dst_row0 = nt * 64; dst_col0 = mt * 64;
  }
  {
    int r = tid >> 2, c0 = (tid & 3) * 16;
    const float* s = src + (size_t)r * src_ld + c0;
#pragma unroll
    for (int q = 0; q < 4; ++q) {
      float4 v = *(const float4*)(s + q * 4);
      t[r][c0 + q * 4 + 0] = v.x; t[r][c0 + q * 4 + 1] = v.y;
      t[r][c0 + q * 4 + 2] = v.z; t[r][c0 + q * 4 + 3] = v.w;
    }
  }
  __syncthreads();
  {
    int d = tid >> 2, mb = (tid & 3) * 16;
    bf16x8 v0, v1;
#pragma unroll
    for (int e = 0; e < 8; ++e) {
      v0[e] = (short)f2bf(t[mb + e][d]);
      v1[e] = (short)f2bf(t[mb + 8 + e][d]);
    }
    u16* dp = dst + (size_t)(dst_row0 + d) * 1024 + dst_col0 + mb;
    *(bf16x8*)(dp) = v0;
    *(bf16x8*)(dp + 8) = v1;
  }
}

// ---------------- GEMM: C[M,N] = A[M,K] x Bt[N,K]^T (+bias, epilogue by MODE) ----------------
// ROUND-11 VERIFIED, byte-identical: BK=32, 2 buffers (32KB -> 4 blocks/CU), vmcnt(0)+barrier
// per K-step, XCD supertile mapping. Bit-identical accumulation order vs BK=64.
// MODE 0: flat 768 blocks; each XCD owns an 8bm x 12bn chunk. Bt=[Wq|Wk|Wv]^T.
//         j<1024: Q*scale -> qk ; 1024<=j<2048: K -> qk ; j>=2048: V -> vt transposed.
// MODE 2: flat 256 blocks; bn = XCD. out f32 d_out[4096,1024] (+bo)
template <int MODE>
__global__ __launch_bounds__(256) void k_gemm(const u16* __restrict__ A, const u16* __restrict__ Bt,
                                              const float* __restrict__ b0, const float* __restrict__ b1,
                                              const float* __restrict__ b2,
                                              u16* __restrict__ outb, u16* __restrict__ outv,
                                              float* __restrict__ outf) {
  constexpr int K = 1024;
  constexpr int NT = 32;  // K-tiles of BK=32
  __shared__ __align__(16) u16 As[2][128 * 32];
  __shared__ __align__(16) u16 Bs[2][128 * 32];
  const int tid = threadIdx.x, wid = tid >> 6, lane = tid & 63;
  const int lo = lane & 15, hi = lane >> 4;
  const int wr = wid >> 1, wc = wid & 1;
  int bm, bn;
  if (MODE == 0) {  // 768 blocks: blockIdx&7 = XCD owns an 8x12 (bm,bn) chunk (bijective)
    const int xcd = blockIdx.x & 7, s = blockIdx.x >> 3;
    bm = (xcd & 3) * 8 + (s & 7);
    bn = (xcd >> 2) * 12 + (s >> 3);
  } else {          // 256 blocks: bn = XCD (one B panel per XCD), bm streams
    bn = blockIdx.x & 7; bm = blockIdx.x >> 3;
  }
  const u16* Ab = A + (size_t)bm * 128 * K;
  const u16* Bb = Bt + (size_t)bn * 128 * K;

  // staging geometry (per wave, 2 instrs each for A and B)
  const int c0 = (wid * 2 + 0) * 64 + lane;   // chunk ids
  const int c1 = c0 + 64;
  const int row0 = c0 >> 2, row1 = c1 >> 2;
  const int g0 = (c0 & 3) ^ ((row0 >> 1) & 3);  // pre-swizzled source k-chunk
  const int g1 = (c1 & 3) ^ ((row1 >> 1) & 3);
  const u16* a_src0 = Ab + (size_t)row0 * K + g0 * 8;
  const u16* a_src1 = Ab + (size_t)row1 * K + g1 * 8;
  const u16* b_src0 = Bb + (size_t)row0 * K + g0 * 8;
  const u16* b_src1 = Bb + (size_t)row1 * K + g1 * 8;
  const int ld0 = (wid * 2 + 0) * 512;  // wave-uniform LDS u16 base (lane*16B implicit)
  const int ld1 = (wid * 2 + 1) * 512;

#define GSTAGE(T, BF)                          \
  {                                            \
    const int kk = (T) * 32;                   \
    gld_lds16(a_src0 + kk, &As[BF][ld0]);      \
    gld_lds16(a_src1 + kk, &As[BF][ld1]);      \
    gld_lds16(b_src0 + kk, &Bs[BF][ld0]);      \
    gld_lds16(b_src1 + kk, &Bs[BF][ld1]);      \
  }

  f32x4 acc[4][4] = {};
  const int fslot = (hi ^ ((lo >> 1) & 3)) * 8;  // frag read slot (2-way free)

  GSTAGE(0, 0)
  int cur = 0;
#pragma unroll 1
  for (int t = 0; t < NT; ++t) {
    asm volatile("s_waitcnt vmcnt(0)" ::: "memory");
    __builtin_amdgcn_s_barrier();
    if (t + 1 < NT) GSTAGE(t + 1, cur ^ 1)
    {
      bf16x8 af[4], bfr[4];
#pragma unroll
      for (int mt = 0; mt < 4; ++mt)
        af[mt] = *(const bf16x8*)(&As[cur][(wr * 64 + mt * 16 + lo) * 32 + fslot]);
#pragma unroll
      for (int nt = 0; nt < 4; ++nt)
        bfr[nt] = *(const bf16x8*)(&Bs[cur][(wc * 64 + nt * 16 + lo) * 32 + fslot]);
#pragma unroll
      for (int mt = 0; mt < 4; ++mt)
#pragma unroll
        for (int nt = 0; nt < 4; ++nt)
          acc[mt][nt] = __builtin_amdgcn_mfma_f32_16x16x32_bf16(af[mt], bfr[nt], acc[mt][nt], 0, 0, 0);
    }
    cur ^= 1;
  }
#undef GSTAGE

#pragma unroll
  for (int mt = 0; mt < 4; ++mt) {
#pragma unroll
    for (int nt = 0; nt < 4; ++nt) {
      const int i0 = bm * 128 + wr * 64 + mt * 16 + hi * 4;
      const int j = bn * 128 + wc * 64 + nt * 16 + lo;
      if (MODE == 0) {
        if (j < 2048) {
#pragma unroll
          for (int rg = 0; rg < 4; ++rg) {
            float v = acc[mt][nt][rg];
            v += (j < 1024) ? b0[j] : b1[j - 1024];
            if (j < 1024) v *= 0.18033688011112042f;  // (1/8)*log2(e): exp2-domain logits
            outb[(size_t)(i0 + rg) * 2048 + j] = f2bf(v);
          }
        } else {  // V: transpose-store, 4 consecutive t packed
          const float bb2 = b2[j - 2048];
          uint2 w;
          w.x = cvtpk(acc[mt][nt][0] + bb2, acc[mt][nt][1] + bb2);
          w.y = cvtpk(acc[mt][nt][2] + bb2, acc[mt][nt][3] + bb2);
          *(uint2*)(outv + (size_t)((i0 >> 11) * 1024 + (j - 2048)) * 2048 + (i0 & 2047)) = w;
        }
      } else {
#pragma unroll
        for (int rg = 0; rg < 4; ++rg)
          outf[(size_t)(i0 + rg) * 1024 + j] = acc[mt][nt][rg] + b0[j];
      }
    }
  }
}

// ---------------- flash attention (32x32 MFMA, in-register P, FIXED-m softmax) ----------------
// Round-12 structure (correct; absmax verified) with the launch-bounds spill bug fixed:
// __launch_bounds__(256, 2) — round 12's (256,3) forced a VGPR cap (84 regs) and spilled
// the f32x16 S-state to scratch (342 MB writes/dispatch, 4x slowdown). With the cap released
// VGPR ~120 (<128 -> 4 waves/SIMD allowed); the 48KB LDS (3 buffers) drives occupancy to
// 3 blocks/CU. Ledger (verified round 12): PRE(T) = vmcnt(0) before barrier, STAGE(T+2)
// into buf (T+2)%3 = tile T-1's buffer. Live: T (SMPV), T+1 (QK), T+2 (staging).
__global__ __launch_bounds__(256, 2) void k_attn(const u16* __restrict__ qk, const u16* __restrict__ vt,
                                                 u16* __restrict__ ao) {
  __shared__ __align__(16) u16 Kl0[3 * 4096];
  __shared__ __align__(16) u16 Vl0[3 * 4096];
  const int tid = threadIdx.x, wid = tid >> 6, lane = tid & 63;
  const int ql = lane & 31, Lh = lane >> 5;
  const int logical = (blockIdx.x & 7) * 64 + (blockIdx.x >> 3);  // bijective (512 = 8*64)
  const int qb = logical & 15, bh = logical >> 4;
  const int b = bh >> 4, h = bh & 15;
  const int qg = qb * 128 + wid * 32 + ql;

  // Q as B-frags (lane: n=q=ql, k=d), kd=0..3
  bf16x8 qB[4];
  const u16* qrow = qk + (size_t)(b * 2048 + qg) * 2048 + h * 64;
#pragma unroll
  for (int kd = 0; kd < 4; ++kd) qB[kd] = *(const bf16x8*)(qrow + kd * 16 + Lh * 8);

  const u16* Kg = qk + 1024 + (size_t)b * 2048 * 2048 + h * 64;  // + t*2048
  const u16* Vg = vt + (size_t)bh * 64 * 2048;                   // + d*2048 + t
  const int sr = lane >> 3, sc = lane & 7;

  f32x16 acco[2] = {};
  float l_part = 0.f;
  f32x16 sA0, sA1, sB0, sB1;

#define STAGE(T)                                                                        \
  {                                                                                     \
    const int sb_ = (T) % 3, t0_ = (T) * 64;                                            \
    _Pragma("unroll") for (int i = 0; i < 2; ++i) {                                     \
      int r = wid * 16 + i * 8 + sr;                                                    \
      int cs = sc ^ (r & 7);                                                            \
      gld_lds16(Kg + (size_t)(t0_ + r) * 2048 + cs * 8, Kl0 + sb_ * 4096 + (wid * 16 + i * 8) * 64); \
      gld_lds16(Vg + (size_t)r * 2048 + t0_ + cs * 8, Vl0 + sb_ * 4096 + (wid * 16 + i * 8) * 64);   \
    }                                                                                   \
  }

#define PRE(T)                                                                          \
  {                                                                                     \
    asm volatile("s_waitcnt vmcnt(0)" ::: "memory");                                    \
    asm volatile("s_barrier" ::: "memory");                                             \
    if ((T) + 2 < 32) STAGE((T) + 2)                                                    \
  }

#define QK(S0, S1, T)                                                                   \
  {                                                                                     \
    const u16* Kb = Kl0 + ((T) % 3) * 4096;                                             \
    S0 = (f32x16){}; S1 = (f32x16){};                                                   \
    bf16x8 ka0[4], ka1[4];                                                              \
    _Pragma("unroll") for (int kd = 0; kd < 4; ++kd) {                                  \
      const int cg = 2 * kd + Lh;                                                       \
      const int r0 = ql, r1 = 32 + ql;                                                  \
      ka0[kd] = *(const bf16x8*)(Kb + r0 * 64 + ((cg ^ (r0 & 7)) * 8));                 \
      ka1[kd] = *(const bf16x8*)(Kb + r1 * 64 + ((cg ^ (r1 & 7)) * 8));                 \
    }                                                                                   \
    __builtin_amdgcn_s_setprio(1);                                                      \
    _Pragma("unroll") for (int kd = 0; kd < 4; ++kd) {                                  \
      S0 = __builtin_amdgcn_mfma_f32_32x32x16_bf16(ka0[kd], qB[kd], S0, 0, 0, 0);       \
      S1 = __builtin_amdgcn_mfma_f32_32x32x16_bf16(ka1[kd], qB[kd], S1, 0, 0, 0);       \
    }                                                                                   \
    __builtin_amdgcn_s_setprio(0);                                                      \
  }

#define SMPV(S0, S1, T)                                                                 \
  {                                                                                     \
    const u16* Vb = Vl0 + ((T) % 3) * 4096;                                             \
    bf16x8 vf[2][4];                                                                    \
    _Pragma("unroll") for (int dt = 0; dt < 2; ++dt) _Pragma("unroll")                  \
        for (int kt = 0; kt < 4; ++kt) {                                                \
          int r = dt * 32 + ql;                                                         \
          int cg = 2 * kt + Lh;                                                         \
          vf[dt][kt] = *(const bf16x8*)(Vb + r * 64 + ((cg ^ (r & 7)) * 8));            \
        }                                                                               \
    unsigned dw0[8], dw1[8];                                                            \
    float ls0 = 0.f, ls1 = 0.f;                                                         \
    _Pragma("unroll") for (int m = 0; m < 8; ++m) {                                     \
      float p0 = ex2(S0[2 * m]), p1 = ex2(S0[2 * m + 1]);                               \
      float p2 = ex2(S1[2 * m]), p3 = ex2(S1[2 * m + 1]);                               \
      ls0 += p0 + p1; ls1 += p2 + p3;                                                   \
      dw0[m] = cvtpk(p0, p1); dw1[m] = cvtpk(p2, p3);                                   \
    }                                                                                   \
    l_part += ls0 + ls1;                                                                \
    __builtin_amdgcn_s_setprio(1);                                                      \
    _Pragma("unroll") for (int kt = 0; kt < 4; ++kt) {                                  \
      const int c = kt & 1;                                                             \
      unsigned w0, w1, w2, w3;                                                          \
      if (kt < 2) { w0 = dw0[4 * c + 0]; w1 = dw0[4 * c + 2];                           \
                    w2 = dw0[4 * c + 1]; w3 = dw0[4 * c + 3]; }                         \
      else        { w0 = dw1[4 * c + 0]; w1 = dw1[4 * c + 2];                           \
                    w2 = dw1[4 * c + 1]; w3 = dw1[4 * c + 3]; }                         \
      u32x2 s0 = __builtin_amdgcn_permlane32_swap(w0, w1, false, false);                \
      u32x2 s1 = __builtin_amdgcn_permlane32_swap(w2, w3, false, false);                \
      union { unsigned u[4]; bf16x8 v; } pb;                                            \
      pb.u[0] = s0[0]; pb.u[1] = s1[0]; pb.u[2] = s0[1]; pb.u[3] = s1[1];               \
      acco[0] = __builtin_amdgcn_mfma_f32_32x32x16_bf16(vf[0][kt], pb.v, acco[0], 0, 0, 0); \
      acco[1] = __builtin_amdgcn_mfma_f32_32x32x16_bf16(vf[1][kt], pb.v, acco[1], 0, 0, 0); \
    }                                                                                   \
    __builtin_amdgcn_s_setprio(0);                                                      \
  }

  // prologue: stage tiles 0,1 ; drain tile0 (cross-wave via barrier) ; QK(0) -> A
  STAGE(0) STAGE(1)
  asm volatile("s_waitcnt vmcnt(4)" ::: "memory");
  asm volatile("s_barrier" ::: "memory");
  QK(sA0, sA1, 0)

#pragma unroll 1
  for (int it = 0; it < 32; it += 2) {
    PRE(it)                     // drains tile it+1; stages tile it+2 into buf (it+2)%3
    QK(sB0, sB1, it + 1)
    SMPV(sA0, sA1, it)
    PRE(it + 1)                 // drains tile it+2; stages tile it+3
    if (it + 2 < 32) QK(sA0, sA1, it + 2)
    SMPV(sB0, sB1, it + 1)
  }
#undef STAGE
#undef PRE
#undef QK
#undef SMPV

  // epilogue: O[q][d], d = 32dt + 8g + 4Lh + (reg&3)
  float lsum = l_part + __shfl_xor(l_part, 32);
  float inv = 1.f / lsum;
  u16* orow = ao + (size_t)(b * 2048 + qg) * 1024 + h * 64;
#pragma unroll
  for (int dt = 0; dt < 2; ++dt)
#pragma unroll
    for (int g = 0; g < 4; ++g) {
      float o0 = acco[dt][4 * g + 0] * inv, o1 = acco[dt][4 * g + 1] * inv;
      float o2 = acco[dt][4 * g + 2] * inv, o3 = acco[dt][4 * g + 3] * inv;
      uint2 w; w.x = cvtpk(o0, o1); w.y = cvtpk(o2, o3);
      *(uint2*)(orow + dt * 32 + g * 8 + Lh * 4) = w;
    }
}

// ---------------- launch ----------------
extern "C" void kernel_launch(void* const* d_in, const int* in_sizes, int n_in,
                              void* d_out, int out_size, void* d_ws, size_t ws_size,
                              hipStream_t stream) {
  const float* x  = (const float*)d_in[0];
  const float* Wq = (const float*)d_in[1];
  const float* bq = (const float*)d_in[2];
  const float* Wk = (const float*)d_in[3];
  const float* bk = (const float*)d_in[4];
  const float* Wv = (const float*)d_in[5];
  const float* bv = (const float*)d_in[6];
  const float* Wo = (const float*)d_in[7];
  const float* bo = (const float*)d_in[8];
  float* out = (float*)d_out;

  char* ws = (char*)d_ws;
  u16* xb    = (u16*)(ws);                       // 8 MB  x bf16 [4096][1024]
  u16* wqkvt = (u16*)(ws + (8u << 20));          // 6 MB  [3072][1024]
  u16* wot   = (u16*)(ws + (14u << 20));         // 2 MB  [1024][1024]
  u16* qk    = (u16*)(ws + (16u << 20));         // 16 MB [4096][2048]
  u16* vt    = (u16*)(ws + (32u << 20));         // 8 MB  [2*16*64][2048]
  u16* aob   = (u16*)(ws + (40u << 20));         // 8 MB  [4096][1024]   (48 MB total)

  k_cast_x<<<4096, 256, 0, stream>>>(x, xb);
  k_prep_w<<<1024, 256, 0, stream>>>(Wq, Wk, Wv, Wo, wqkvt, wot);
  k_gemm<0><<<768, 256, 0, stream>>>(xb, wqkvt, bq, bk, bv, qk, vt, nullptr);
  k_attn<<<512, 256, 0, stream>>>(qk, vt, aob);
  k_gemm<2><<<256, 256, 0, stream>>>(aob, wot, bo, nullptr, nullptr, nullptr, nullptr, out);
}

// Round 14
// 113.998 us; speedup vs baseline: 2.2661x; 1.0098x over previous
//
#include <hip/hip_runtime.h>
#include <hip/hip_bf16.h>

#define DEV __device__ __forceinline__

typedef unsigned short u16;
typedef __attribute__((ext_vector_type(8))) short bf16x8;
typedef __attribute__((ext_vector_type(4))) float f32x4;
typedef __attribute__((ext_vector_type(16))) float f32x16;
typedef __attribute__((ext_vector_type(4))) unsigned short us4;
typedef __attribute__((ext_vector_type(2))) unsigned u32x2;

DEV void gld_lds16(const void* g, void* l) {
  __builtin_amdgcn_global_load_lds((const __attribute__((address_space(1))) void*)g,
                                   (__attribute__((address_space(3))) void*)l, 16, 0, 0);
}

DEV u16 f2bf(float x) {  // RNE f32->bf16 (inputs finite)
  union { float f; unsigned u; } v; v.f = x;
  unsigned r = v.u + 0x7FFFu + ((v.u >> 16) & 1u);
  return (u16)(r >> 16);
}

DEV float ex2(float x) {  // 2^x
  float r; asm("v_exp_f32 %0, %1" : "=v"(r) : "v"(x)); return r;
}

DEV unsigned cvtpk(float a, float b) {  // [bf16(b)<<16 | bf16(a)]
  unsigned r; asm("v_cvt_pk_bf16_f32 %0, %1, %2" : "=v"(r) : "v"(a), "v"(b)); return r;
}

// ---------------- fused prep: weight transpose-pack (blocks 0..1023) + x cast (1024..5119) ----------------
// Wq/Wk/Wv: [H][1024][64] -> wqkvt rows {0,1024,2048}+(h*64+d), cols m ; Wo -> wot[n][m]
__global__ __launch_bounds__(256) void k_prep(const float* __restrict__ x,
                                              const float* __restrict__ Wq, const float* __restrict__ Wk,
                                              const float* __restrict__ Wv, const float* __restrict__ Wo,
                                              u16* __restrict__ xb,
                                              u16* __restrict__ wqkvt, u16* __restrict__ wot) {
  __shared__ float t[64][65];
  const int bb = blockIdx.x, tid = threadIdx.x;
  if (bb >= 1024) {  // ---- cast x to bf16 ----
    int i = ((bb - 1024) * 256 + tid) * 4;
    const float4 v = *(const float4*)(x + i);
    us4 o; o.x = f2bf(v.x); o.y = f2bf(v.y); o.z = f2bf(v.z); o.w = f2bf(v.w);
    *(us4*)(xb + i) = o;
    return;
  }
  // ---- weight transpose-pack ----
  const float* src; u16* dst; int src_ld, dst_row0, dst_col0;
  if (bb < 768) {
    int which = bb >> 8, h = (bb >> 4) & 15, m0 = (bb & 15) * 64;
    const float* W = which == 0 ? Wq : (which == 1 ? Wk : Wv);
    src = W + h * 65536 + m0 * 64; src_ld = 64;
    dst = wqkvt + which * (1024 * 1024);
    dst_row0 = h * 64; dst_col0 = m0;
  } else {
    int t2 = bb - 768, mt = t2 >> 4, nt = t2 & 15;
    src = Wo + (size_t)(mt * 64) * 1024 + nt * 64; src_ld = 1024;
    dst = wot; dst_row0 = nt * 64; dst_col0 = mt * 64;
  }
  {
    int r = tid >> 2, c0 = (tid & 3) * 16;
    const float* s = src + (size_t)r * src_ld + c0;
#pragma unroll
    for (int q = 0; q < 4; ++q) {
      float4 v = *(const float4*)(s + q * 4);
      t[r][c0 + q * 4 + 0] = v.x; t[r][c0 + q * 4 + 1] = v.y;
      t[r][c0 + q * 4 + 2] = v.z; t[r][c0 + q * 4 + 3] = v.w;
    }
  }
  __syncthreads();
  {
    int d = tid >> 2, mb = (tid & 3) * 16;
    bf16x8 v0, v1;
#pragma unroll
    for (int e = 0; e < 8; ++e) {
      v0[e] = (short)f2bf(t[mb + e][d]);
      v1[e] = (short)f2bf(t[mb + 8 + e][d]);
    }
    u16* dp = dst + (size_t)(dst_row0 + d) * 1024 + dst_col0 + mb;
    *(bf16x8*)(dp) = v0;
    *(bf16x8*)(dp + 8) = v1;
  }
}

// ---------------- GEMM: C[M,N] = A[M,K] x Bt[N,K]^T (+bias, epilogue by MODE) ----------------
// BK=32, 3 buffers (48KB -> 3 blocks/CU), counted vmcnt(4) pipeline (round-9 gemm ledger,
// now proven cross-wave safe): every wave drains tile t at its OWN vmcnt(4) BEFORE the
// barrier; only tile t+1's 4 loads ride the barrier, and no wave reads t+1 until after the
// NEXT barrier. Math bit-identical to rounds 11-13.
// MODE 0: flat 768 blocks; each XCD owns an 8bm x 12bn chunk. Bt=[Wq|Wk|Wv]^T.
//         j<1024: Q*scale -> qk ; 1024<=j<2048: K -> qk ; j>=2048: V -> vt transposed.
// MODE 2: flat 256 blocks; bn = XCD. out f32 d_out[4096,1024] (+bo)
template <int MODE>
__global__ __launch_bounds__(256) void k_gemm(const u16* __restrict__ A, const u16* __restrict__ Bt,
                                              const float* __restrict__ b0, const float* __restrict__ b1,
                                              const float* __restrict__ b2,
                                              u16* __restrict__ outb, u16* __restrict__ outv,
                                              float* __restrict__ outf) {
  constexpr int K = 1024;
  constexpr int NT = 32;  // K-tiles of BK=32
  __shared__ __align__(16) u16 As[3][128 * 32];
  __shared__ __align__(16) u16 Bs[3][128 * 32];
  const int tid = threadIdx.x, wid = tid >> 6, lane = tid & 63;
  const int lo = lane & 15, hi = lane >> 4;
  const int wr = wid >> 1, wc = wid & 1;
  int bm, bn;
  if (MODE == 0) {  // 768 blocks: blockIdx&7 = XCD owns an 8x12 (bm,bn) chunk (bijective)
    const int xcd = blockIdx.x & 7, s = blockIdx.x >> 3;
    bm = (xcd & 3) * 8 + (s & 7);
    bn = (xcd >> 2) * 12 + (s >> 3);
  } else {          // 256 blocks: bn = XCD (one B panel per XCD), bm streams
    bn = blockIdx.x & 7; bm = blockIdx.x >> 3;
  }
  const u16* Ab = A + (size_t)bm * 128 * K;
  const u16* Bb = Bt + (size_t)bn * 128 * K;

  // staging geometry (per wave, 2 instrs each for A and B)
  const int c0 = (wid * 2 + 0) * 64 + lane;   // chunk ids
  const int c1 = c0 + 64;
  const int row0 = c0 >> 2, row1 = c1 >> 2;
  const int g0 = (c0 & 3) ^ ((row0 >> 1) & 3);  // pre-swizzled source k-chunk
  const int g1 = (c1 & 3) ^ ((row1 >> 1) & 3);
  const u16* a_src0 = Ab + (size_t)row0 * K + g0 * 8;
  const u16* a_src1 = Ab + (size_t)row1 * K + g1 * 8;
  const u16* b_src0 = Bb + (size_t)row0 * K + g0 * 8;
  const u16* b_src1 = Bb + (size_t)row1 * K + g1 * 8;
  const int ld0 = (wid * 2 + 0) * 512;  // wave-uniform LDS u16 base (lane*16B implicit)
  const int ld1 = (wid * 2 + 1) * 512;

#define GSTAGE(T, BF)                          \
  {                                            \
    const int kk = (T) * 32;                   \
    gld_lds16(a_src0 + kk, &As[BF][ld0]);      \
    gld_lds16(a_src1 + kk, &As[BF][ld1]);      \
    gld_lds16(b_src0 + kk, &Bs[BF][ld0]);      \
    gld_lds16(b_src1 + kk, &Bs[BF][ld1]);      \
  }

  f32x4 acc[4][4] = {};
  const int fslot = (hi ^ ((lo >> 1) & 3)) * 8;  // frag read slot (2-way free)

  GSTAGE(0, 0) GSTAGE(1, 1)
  int cur = 0, sbuf = 2;
#pragma unroll 1
  for (int t = 0; t < NT; ++t) {
    // drain tile t (own loads) BEFORE barrier; leave tile t+1's 4 loads in flight
    if (t < NT - 1) asm volatile("s_waitcnt vmcnt(4)" ::: "memory");
    else            asm volatile("s_waitcnt vmcnt(0)" ::: "memory");
    __builtin_amdgcn_s_barrier();
    if (t + 2 < NT) {
      GSTAGE(t + 2, sbuf)  // buf (t+2)%3 = buf read in phase t-1 (all reads pre-barrier)
      sbuf = (sbuf == 2) ? 0 : sbuf + 1;
    }
    {
      bf16x8 af[4], bfr[4];
#pragma unroll
      for (int mt = 0; mt < 4; ++mt)
        af[mt] = *(const bf16x8*)(&As[cur][(wr * 64 + mt * 16 + lo) * 32 + fslot]);
#pragma unroll
      for (int nt = 0; nt < 4; ++nt)
        bfr[nt] = *(const bf16x8*)(&Bs[cur][(wc * 64 + nt * 16 + lo) * 32 + fslot]);
#pragma unroll
      for (int mt = 0; mt < 4; ++mt)
#pragma unroll
        for (int nt = 0; nt < 4; ++nt)
          acc[mt][nt] = __builtin_amdgcn_mfma_f32_16x16x32_bf16(af[mt], bfr[nt], acc[mt][nt], 0, 0, 0);
    }
    cur = (cur == 2) ? 0 : cur + 1;
  }
#undef GSTAGE

#pragma unroll
  for (int mt = 0; mt < 4; ++mt) {
#pragma unroll
    for (int nt = 0; nt < 4; ++nt) {
      const int i0 = bm * 128 + wr * 64 + mt * 16 + hi * 4;
      const int j = bn * 128 + wc * 64 + nt * 16 + lo;
      if (MODE == 0) {
        if (j < 2048) {
#pragma unroll
          for (int rg = 0; rg < 4; ++rg) {
            float v = acc[mt][nt][rg];
            v += (j < 1024) ? b0[j] : b1[j - 1024];
            if (j < 1024) v *= 0.18033688011112042f;  // (1/8)*log2(e): exp2-domain logits
            outb[(size_t)(i0 + rg) * 2048 + j] = f2bf(v);
          }
        } else {  // V: transpose-store, 4 consecutive t packed
          const float bb2 = b2[j - 2048];
          uint2 w;
          w.x = cvtpk(acc[mt][nt][0] + bb2, acc[mt][nt][1] + bb2);
          w.y = cvtpk(acc[mt][nt][2] + bb2, acc[mt][nt][3] + bb2);
          *(uint2*)(outv + (size_t)((i0 >> 11) * 1024 + (j - 2048)) * 2048 + (i0 & 2047)) = w;
        }
      } else {
#pragma unroll
        for (int rg = 0; rg < 4; ++rg)
          outf[(size_t)(i0 + rg) * 1024 + j] = acc[mt][nt][rg] + b0[j];
      }
    }
  }
}

// ---------------- flash attention (32x32 MFMA, in-register P, FIXED-m softmax) ----------------
// ROUND-13 VERIFIED, byte-identical. 3 K/V buffers, PRE = vmcnt(0) before barrier, T15
// two-tile, fixed-m softmax, bijective XCD swizzle, setprio. Grid-capped at 2 blocks/CU.
__global__ __launch_bounds__(256, 2) void k_attn(const u16* __restrict__ qk, const u16* __restrict__ vt,
                                                 u16* __restrict__ ao) {
  __shared__ __align__(16) u16 Kl0[3 * 4096];
  __shared__ __align__(16) u16 Vl0[3 * 4096];
  const int tid = threadIdx.x, wid = tid >> 6, lane = tid & 63;
  const int ql = lane & 31, Lh = lane >> 5;
  const int logical = (blockIdx.x & 7) * 64 + (blockIdx.x >> 3);  // bijective (512 = 8*64)
  const int qb = logical & 15, bh = logical >> 4;
  const int b = bh >> 4, h = bh & 15;
  const int qg = qb * 128 + wid * 32 + ql;

  // Q as B-frags (lane: n=q=ql, k=d), kd=0..3
  bf16x8 qB[4];
  const u16* qrow = qk + (size_t)(b * 2048 + qg) * 2048 + h * 64;
#pragma unroll
  for (int kd = 0; kd < 4; ++kd) qB[kd] = *(const bf16x8*)(qrow + kd * 16 + Lh * 8);

  const u16* Kg = qk + 1024 + (size_t)b * 2048 * 2048 + h * 64;  // + t*2048
  const u16* Vg = vt + (size_t)bh * 64 * 2048;                   // + d*2048 + t
  const int sr = lane >> 3, sc = lane & 7;

  f32x16 acco[2] = {};
  float l_part = 0.f;
  f32x16 sA0, sA1, sB0, sB1;

#define STAGE(T)                                                                        \
  {                                                                                     \
    const int sb_ = (T) % 3, t0_ = (T) * 64;                                            \
    _Pragma("unroll") for (int i = 0; i < 2; ++i) {                                     \
      int r = wid * 16 + i * 8 + sr;                                                    \
      int cs = sc ^ (r & 7);                                                            \
      gld_lds16(Kg + (size_t)(t0_ + r) * 2048 + cs * 8, Kl0 + sb_ * 4096 + (wid * 16 + i * 8) * 64); \
      gld_lds16(Vg + (size_t)r * 2048 + t0_ + cs * 8, Vl0 + sb_ * 4096 + (wid * 16 + i * 8) * 64);   \
    }                                                                                   \
  }

#define PRE(T)                                                                          \
  {                                                                                     \
    asm volatile("s_waitcnt vmcnt(0)" ::: "memory");                                    \
    asm volatile("s_barrier" ::: "memory");                                             \
    if ((T) + 2 < 32) STAGE((T) + 2)                                                    \
  }

#define QK(S0, S1, T)                                                                   \
  {                                                                                     \
    const u16* Kb = Kl0 + ((T) % 3) * 4096;                                             \
    S0 = (f32x16){}; S1 = (f32x16){};                                                   \
    bf16x8 ka0[4], ka1[4];                                                              \
    _Pragma("unroll") for (int kd = 0; kd < 4; ++kd) {                                  \
      const int cg = 2 * kd + Lh;                                                       \
      const int r0 = ql, r1 = 32 + ql;                                                  \
      ka0[kd] = *(const bf16x8*)(Kb + r0 * 64 + ((cg ^ (r0 & 7)) * 8));                 \
      ka1[kd] = *(const bf16x8*)(Kb + r1 * 64 + ((cg ^ (r1 & 7)) * 8));                 \
    }                                                                                   \
    __builtin_amdgcn_s_setprio(1);                                                      \
    _Pragma("unroll") for (int kd = 0; kd < 4; ++kd) {                                  \
      S0 = __builtin_amdgcn_mfma_f32_32x32x16_bf16(ka0[kd], qB[kd], S0, 0, 0, 0);       \
      S1 = __builtin_amdgcn_mfma_f32_32x32x16_bf16(ka1[kd], qB[kd], S1, 0, 0, 0);       \
    }                                                                                   \
    __builtin_amdgcn_s_setprio(0);                                                      \
  }

#define SMPV(S0, S1, T)                                                                 \
  {                                                                                     \
    const u16* Vb = Vl0 + ((T) % 3) * 4096;                                             \
    bf16x8 vf[2][4];                                                                    \
    _Pragma("unroll") for (int dt = 0; dt < 2; ++dt) _Pragma("unroll")                  \
        for (int kt = 0; kt < 4; ++kt) {                                                \
          int r = dt * 32 + ql;                                                         \
          int cg = 2 * kt + Lh;                                                         \
          vf[dt][kt] = *(const bf16x8*)(Vb + r * 64 + ((cg ^ (r & 7)) * 8));            \
        }                                                                               \
    unsigned dw0[8], dw1[8];                                                            \
    float ls0 = 0.f, ls1 = 0.f;                                                         \
    _Pragma("unroll") for (int m = 0; m < 8; ++m) {                                     \
      float p0 = ex2(S0[2 * m]), p1 = ex2(S0[2 * m + 1]);                               \
      float p2 = ex2(S1[2 * m]), p3 = ex2(S1[2 * m + 1]);                               \
      ls0 += p0 + p1; ls1 += p2 + p3;                                                   \
      dw0[m] = cvtpk(p0, p1); dw1[m] = cvtpk(p2, p3);                                   \
    }                                                                                   \
    l_part += ls0 + ls1;                                                                \
    __builtin_amdgcn_s_setprio(1);                                                      \
    _Pragma("unroll") for (int kt = 0; kt < 4; ++kt) {                                  \
      const int c = kt & 1;                                                             \
      unsigned w0, w1, w2, w3;                                                          \
      if (kt < 2) { w0 = dw0[4 * c + 0]; w1 = dw0[4 * c + 2];                           \
                    w2 = dw0[4 * c + 1]; w3 = dw0[4 * c + 3]; }                         \
      else        { w0 = dw1[4 * c + 0]; w1 = dw1[4 * c + 2];                           \
                    w2 = dw1[4 * c + 1]; w3 = dw1[4 * c + 3]; }                         \
      u32x2 s0 = __builtin_amdgcn_permlane32_swap(w0, w1, false, false);                \
      u32x2 s1 = __builtin_amdgcn_permlane32_swap(w2, w3, false, false);                \
      union { unsigned u[4]; bf16x8 v; } pb;                                            \
      pb.u[0] = s0[0]; pb.u[1] = s1[0]; pb.u[2] = s0[1]; pb.u[3] = s1[1];               \
      acco[0] = __builtin_amdgcn_mfma_f32_32x32x16_bf16(vf[0][kt], pb.v, acco[0], 0, 0, 0); \
      acco[1] = __builtin_amdgcn_mfma_f32_32x32x16_bf16(vf[1][kt], pb.v, acco[1], 0, 0, 0); \
    }                                                                                   \
    __builtin_amdgcn_s_setprio(0);                                                      \
  }

  // prologue: stage tiles 0,1 ; drain tile0 (cross-wave via barrier) ; QK(0) -> A
  STAGE(0) STAGE(1)
  asm volatile("s_waitcnt vmcnt(4)" ::: "memory");
  asm volatile("s_barrier" ::: "memory");
  QK(sA0, sA1, 0)

#pragma unroll 1
  for (int it = 0; it < 32; it += 2) {
    PRE(it)                     // drains tile it+1; stages tile it+2 into buf (it+2)%3
    QK(sB0, sB1, it + 1)
    SMPV(sA0, sA1, it)
    PRE(it + 1)                 // drains tile it+2; stages tile it+3
    if (it + 2 < 32) QK(sA0, sA1, it + 2)
    SMPV(sB0, sB1, it + 1)
  }
#undef STAGE
#undef PRE
#undef QK
#undef SMPV

  // epilogue: O[q][d], d = 32dt + 8g + 4Lh + (reg&3)
  float lsum = l_part + __shfl_xor(l_part, 32);
  float inv = 1.f / lsum;
  u16* orow = ao + (size_t)(b * 2048 + qg) * 1024 + h * 64;
#pragma unroll
  for (int dt = 0; dt < 2; ++dt)
#pragma unroll
    for (int g = 0; g < 4; ++g) {
      float o0 = acco[dt][4 * g + 0] * inv, o1 = acco[dt][4 * g + 1] * inv;
      float o2 = acco[dt][4 * g + 2] * inv, o3 = acco[dt][4 * g + 3] * inv;
      uint2 w; w.x = cvtpk(o0, o1); w.y = cvtpk(o2, o3);
      *(uint2*)(orow + dt * 32 + g * 8 + Lh * 4) = w;
    }
}

// ---------------- launch ----------------
extern "C" void kernel_launch(void* const* d_in, const int* in_sizes, int n_in,
                              void* d_out, int out_size, void* d_ws, size_t ws_size,
                              hipStream_t stream) {
  const float* x  = (const float*)d_in[0];
  const float* Wq = (const float*)d_in[1];
  const float* bq = (const float*)d_in[2];
  const float* Wk = (const float*)d_in[3];
  const float* bk = (const float*)d_in[4];
  const float* Wv = (const float*)d_in[5];
  const float* bv = (const float*)d_in[6];
  const float* Wo = (const float*)d_in[7];
  const float* bo = (const float*)d_in[8];
  float* out = (float*)d_out;

  char* ws = (char*)d_ws;
  u16* xb    = (u16*)(ws);                       // 8 MB  x bf16 [4096][1024]
  u16* wqkvt = (u16*)(ws + (8u << 20));          // 6 MB  [3072][1024]
  u16* wot   = (u16*)(ws + (14u << 20));         // 2 MB  [1024][1024]
  u16* qk    = (u16*)(ws + (16u << 20));         // 16 MB [4096][2048]
  u16* vt    = (u16*)(ws + (32u << 20));         // 8 MB  [2*16*64][2048]
  u16* aob   = (u16*)(ws + (40u << 20));         // 8 MB  [4096][1024]   (48 MB total)

  k_prep<<<5120, 256, 0, stream>>>(x, Wq, Wk, Wv, Wo, xb, wqkvt, wot);
  k_gemm<0><<<768, 256, 0, stream>>>(xb, wqkvt, bq, bk, bv, qk, vt, nullptr);
  k_attn<<<512, 256, 0, stream>>>(qk, vt, aob);
  k_gemm<2><<<256, 256, 0, stream>>>(aob, wot, bo, nullptr, nullptr, nullptr, nullptr, out);
}

// Round 19
// 113.682 us; speedup vs baseline: 2.2724x; 1.0028x over previous
//
#include <hip/hip_runtime.h>
#include <hip/hip_bf16.h>

#define DEV __device__ __forceinline__

typedef unsigned short u16;
typedef __attribute__((ext_vector_type(8))) short bf16x8;
typedef __attribute__((ext_vector_type(4))) float f32x4;
typedef __attribute__((ext_vector_type(16))) float f32x16;
typedef __attribute__((ext_vector_type(4))) unsigned short us4;
typedef __attribute__((ext_vector_type(2))) unsigned u32x2;

DEV void gld_lds16(const void* g, void* l) {
  __builtin_amdgcn_global_load_lds((const __attribute__((address_space(1))) void*)g,
                                   (__attribute__((address_space(3))) void*)l, 16, 0, 0);
}

DEV u16 f2bf(float x) {  // RNE f32->bf16 (inputs finite)
  union { float f; unsigned u; } v; v.f = x;
  unsigned r = v.u + 0x7FFFu + ((v.u >> 16) & 1u);
  return (u16)(r >> 16);
}

DEV float ex2(float x) {  // 2^x
  float r; asm("v_exp_f32 %0, %1" : "=v"(r) : "v"(x)); return r;
}

DEV unsigned cvtpk(float a, float b) {  // [bf16(b)<<16 | bf16(a)]
  unsigned r; asm("v_cvt_pk_bf16_f32 %0, %1, %2" : "=v"(r) : "v"(a), "v"(b)); return r;
}

// ---------------- fused prep: weight transpose-pack (blocks 0..1023) + x cast (1024..5119) ----------------
// Wq/Wk/Wv: [H][1024][64] -> wqkvt rows {0,1024,2048}+(h*64+d), cols m ; Wo -> wot[n][m]
__global__ __launch_bounds__(256) void k_prep(const float* __restrict__ x,
                                              const float* __restrict__ Wq, const float* __restrict__ Wk,
                                              const float* __restrict__ Wv, const float* __restrict__ Wo,
                                              u16* __restrict__ xb,
                                              u16* __restrict__ wqkvt, u16* __restrict__ wot) {
  __shared__ float t[64][65];
  const int bb = blockIdx.x, tid = threadIdx.x;
  if (bb >= 1024) {  // ---- cast x to bf16 ----
    int i = ((bb - 1024) * 256 + tid) * 4;
    const float4 v = *(const float4*)(x + i);
    us4 o; o.x = f2bf(v.x); o.y = f2bf(v.y); o.z = f2bf(v.z); o.w = f2bf(v.w);
    *(us4*)(xb + i) = o;
    return;
  }
  // ---- weight transpose-pack ----
  const float* src; u16* dst; int src_ld, dst_row0, dst_col0;
  if (bb < 768) {
    int which = bb >> 8, h = (bb >> 4) & 15, m0 = (bb & 15) * 64;
    const float* W = which == 0 ? Wq : (which == 1 ? Wk : Wv);
    src = W + h * 65536 + m0 * 64; src_ld = 64;
    dst = wqkvt + which * (1024 * 1024);
    dst_row0 = h * 64; dst_col0 = m0;
  } else {
    int t2 = bb - 768, mt = t2 >> 4, nt = t2 & 15;
    src = Wo + (size_t)(mt * 64) * 1024 + nt * 64; src_ld = 1024;
    dst = wot; dst_row0 = nt * 64; dst_col0 = mt * 64;
  }
  {
    int r = tid >> 2, c0 = (tid & 3) * 16;
    const float* s = src + (size_t)r * src_ld + c0;
#pragma unroll
    for (int q = 0; q < 4; ++q) {
      float4 v = *(const float4*)(s + q * 4);
      t[r][c0 + q * 4 + 0] = v.x; t[r][c0 + q * 4 + 1] = v.y;
      t[r][c0 + q * 4 + 2] = v.z; t[r][c0 + q * 4 + 3] = v.w;
    }
  }
  __syncthreads();
  {
    int d = tid >> 2, mb = (tid & 3) * 16;
    bf16x8 v0, v1;
#pragma unroll
    for (int e = 0; e < 8; ++e) {
      v0[e] = (short)f2bf(t[mb + e][d]);
      v1[e] = (short)f2bf(t[mb + 8 + e][d]);
    }
    u16* dp = dst + (size_t)(dst_row0 + d) * 1024 + dst_col0 + mb;
    *(bf16x8*)(dp) = v0;
    *(bf16x8*)(dp + 8) = v1;
  }
}

// ---------------- GEMM: C[M,N] = A[M,K] x Bt[N,K]^T (+bias, epilogue by MODE) ----------------
// BK=32, 3 buffers (48KB -> 3 blocks/CU), counted vmcnt(4) pipeline (cross-wave safe:
// every wave drains tile t at its OWN vmcnt(4) BEFORE the barrier; only tile t+1's 4 loads
// ride the barrier, and no wave reads t+1 until after the NEXT barrier).
// MODE 0: flat 768 blocks; each XCD owns an 8bm x 12bn chunk. Bt=[Wq|Wk|Wv]^T.
//         j<1024: Q*scale -> qk ; 1024<=j<2048: K -> qk ; j>=2048: V -> vt transposed.
// MODE 2: flat 256 blocks; bn = XCD. out f32 d_out[4096,1024] (+bo)
template <int MODE>
__global__ __launch_bounds__(256) void k_gemm(const u16* __restrict__ A, const u16* __restrict__ Bt,
                                              const float* __restrict__ b0, const float* __restrict__ b1,
                                              const float* __restrict__ b2,
                                              u16* __restrict__ outb, u16* __restrict__ outv,
                                              float* __restrict__ outf) {
  constexpr int K = 1024;
  constexpr int NT = 32;  // K-tiles of BK=32
  __shared__ __align__(16) u16 As[3][128 * 32];
  __shared__ __align__(16) u16 Bs[3][128 * 32];
  const int tid = threadIdx.x, wid = tid >> 6, lane = tid & 63;
  const int lo = lane & 15, hi = lane >> 4;
  const int wr = wid >> 1, wc = wid & 1;
  int bm, bn;
  if (MODE == 0) {  // 768 blocks: blockIdx&7 = XCD owns an 8x12 (bm,bn) chunk (bijective)
    const int xcd = blockIdx.x & 7, s = blockIdx.x >> 3;
    bm = (xcd & 3) * 8 + (s & 7);
    bn = (xcd >> 2) * 12 + (s >> 3);
  } else {          // 256 blocks: bn = XCD (one B panel per XCD), bm streams
    bn = blockIdx.x & 7; bm = blockIdx.x >> 3;
  }
  const u16* Ab = A + (size_t)bm * 128 * K;
  const u16* Bb = Bt + (size_t)bn * 128 * K;

  // staging geometry (per wave, 2 instrs each for A and B)
  const int c0 = (wid * 2 + 0) * 64 + lane;   // chunk ids
  const int c1 = c0 + 64;
  const int row0 = c0 >> 2, row1 = c1 >> 2;
  const int g0 = (c0 & 3) ^ ((row0 >> 1) & 3);  // pre-swizzled source k-chunk
  const int g1 = (c1 & 3) ^ ((row1 >> 1) & 3);
  const u16* a_src0 = Ab + (size_t)row0 * K + g0 * 8;
  const u16* a_src1 = Ab + (size_t)row1 * K + g1 * 8;
  const u16* b_src0 = Bb + (size_t)row0 * K + g0 * 8;
  const u16* b_src1 = Bb + (size_t)row1 * K + g1 * 8;
  const int ld0 = (wid * 2 + 0) * 512;  // wave-uniform LDS u16 base (lane*16B implicit)
  const int ld1 = (wid * 2 + 1) * 512;

#define GSTAGE(T, BF)                          \
  {                                            \
    const int kk = (T) * 32;                   \
    gld_lds16(a_src0 + kk, &As[BF][ld0]);      \
    gld_lds16(a_src1 + kk, &As[BF][ld1]);      \
    gld_lds16(b_src0 + kk, &Bs[BF][ld0]);      \
    gld_lds16(b_src1 + kk, &Bs[BF][ld1]);      \
  }

  f32x4 acc[4][4] = {};
  const int fslot = (hi ^ ((lo >> 1) & 3)) * 8;  // frag read slot (2-way free)

  GSTAGE(0, 0) GSTAGE(1, 1)
  int cur = 0, sbuf = 2;
#pragma unroll 1
  for (int t = 0; t < NT; ++t) {
    // drain tile t (own loads) BEFORE barrier; leave tile t+1's 4 loads in flight
    if (t < NT - 1) asm volatile("s_waitcnt vmcnt(4)" ::: "memory");
    else            asm volatile("s_waitcnt vmcnt(0)" ::: "memory");
    __builtin_amdgcn_s_barrier();
    if (t + 2 < NT) {
      GSTAGE(t + 2, sbuf)  // buf (t+2)%3 = buf read in phase t-1 (all reads pre-barrier)
      sbuf = (sbuf == 2) ? 0 : sbuf + 1;
    }
    {
      bf16x8 af[4], bfr[4];
#pragma unroll
      for (int mt = 0; mt < 4; ++mt)
        af[mt] = *(const bf16x8*)(&As[cur][(wr * 64 + mt * 16 + lo) * 32 + fslot]);
#pragma unroll
      for (int nt = 0; nt < 4; ++nt)
        bfr[nt] = *(const bf16x8*)(&Bs[cur][(wc * 64 + nt * 16 + lo) * 32 + fslot]);
#pragma unroll
      for (int mt = 0; mt < 4; ++mt)
#pragma unroll
        for (int nt = 0; nt < 4; ++nt)
          acc[mt][nt] = __builtin_amdgcn_mfma_f32_16x16x32_bf16(af[mt], bfr[nt], acc[mt][nt], 0, 0, 0);
    }
    cur = (cur == 2) ? 0 : cur + 1;
  }
#undef GSTAGE

#pragma unroll
  for (int mt = 0; mt < 4; ++mt) {
#pragma unroll
    for (int nt = 0; nt < 4; ++nt) {
      const int i0 = bm * 128 + wr * 64 + mt * 16 + hi * 4;
      const int j = bn * 128 + wc * 64 + nt * 16 + lo;
      if (MODE == 0) {
        if (j < 2048) {
#pragma unroll
          for (int rg = 0; rg < 4; ++rg) {
            float v = acc[mt][nt][rg];
            v += (j < 1024) ? b0[j] : b1[j - 1024];
            if (j < 1024) v *= 0.18033688011112042f;  // (1/8)*log2(e): exp2-domain logits
            outb[(size_t)(i0 + rg) * 2048 + j] = f2bf(v);
          }
        } else {  // V: transpose-store, 4 consecutive t packed
          const float bb2 = b2[j - 2048];
          uint2 w;
          w.x = cvtpk(acc[mt][nt][0] + bb2, acc[mt][nt][1] + bb2);
          w.y = cvtpk(acc[mt][nt][2] + bb2, acc[mt][nt][3] + bb2);
          *(uint2*)(outv + (size_t)((i0 >> 11) * 1024 + (j - 2048)) * 2048 + (i0 & 2047)) = w;
        }
      } else {
#pragma unroll
        for (int rg = 0; rg < 4; ++rg)
          outf[(size_t)(i0 + rg) * 1024 + j] = acc[mt][nt][rg] + b0[j];
      }
    }
  }
}

// ---------------- flash attention (32x32 MFMA, in-register P, FIXED-m softmax) ----------------
// ROUND-14 GOLDEN, byte-identical. 3 K/V buffers, PRE = vmcnt(0) before barrier, T15
// two-tile, fixed-m softmax, bijective XCD swizzle, setprio. Grid-capped at 2 blocks/CU.
__global__ __launch_bounds__(256, 2) void k_attn(const u16* __restrict__ qk, const u16* __restrict__ vt,
                                                 u16* __restrict__ ao) {
  __shared__ __align__(16) u16 Kl0[3 * 4096];
  __shared__ __align__(16) u16 Vl0[3 * 4096];
  const int tid = threadIdx.x, wid = tid >> 6, lane = tid & 63;
  const int ql = lane & 31, Lh = lane >> 5;
  const int logical = (blockIdx.x & 7) * 64 + (blockIdx.x >> 3);  // bijective (512 = 8*64)
  const int qb = logical & 15, bh = logical >> 4;
  const int b = bh >> 4, h = bh & 15;
  const int qg = qb * 128 + wid * 32 + ql;

  // Q as B-frags (lane: n=q=ql, k=d), kd=0..3
  bf16x8 qB[4];
  const u16* qrow = qk + (size_t)(b * 2048 + qg) * 2048 + h * 64;
#pragma unroll
  for (int kd = 0; kd < 4; ++kd) qB[kd] = *(const bf16x8*)(qrow + kd * 16 + Lh * 8);

  const u16* Kg = qk + 1024 + (size_t)b * 2048 * 2048 + h * 64;  // + t*2048
  const u16* Vg = vt + (size_t)bh * 64 * 2048;                   // + d*2048 + t
  const int sr = lane >> 3, sc = lane & 7;

  f32x16 acco[2] = {};
  float l_part = 0.f;
  f32x16 sA0, sA1, sB0, sB1;

#define STAGE(T)                                                                        \
  {                                                                                     \
    const int sb_ = (T) % 3, t0_ = (T) * 64;                                            \
    _Pragma("unroll") for (int i = 0; i < 2; ++i) {                                     \
      int r = wid * 16 + i * 8 + sr;                                                    \
      int cs = sc ^ (r & 7);                                                            \
      gld_lds16(Kg + (size_t)(t0_ + r) * 2048 + cs * 8, Kl0 + sb_ * 4096 + (wid * 16 + i * 8) * 64); \
      gld_lds16(Vg + (size_t)r * 2048 + t0_ + cs * 8, Vl0 + sb_ * 4096 + (wid * 16 + i * 8) * 64);   \
    }                                                                                   \
  }

#define PRE(T)                                                                          \
  {                                                                                     \
    asm volatile("s_waitcnt vmcnt(0)" ::: "memory");                                    \
    asm volatile("s_barrier" ::: "memory");                                             \
    if ((T) + 2 < 32) STAGE((T) + 2)                                                    \
  }

#define QK(S0, S1, T)                                                                   \
  {                                                                                     \
    const u16* Kb = Kl0 + ((T) % 3) * 4096;                                             \
    S0 = (f32x16){}; S1 = (f32x16){};                                                   \
    bf16x8 ka0[4], ka1[4];                                                              \
    _Pragma("unroll") for (int kd = 0; kd < 4; ++kd) {                                  \
      const int cg = 2 * kd + Lh;                                                       \
      const int r0 = ql, r1 = 32 + ql;                                                  \
      ka0[kd] = *(const bf16x8*)(Kb + r0 * 64 + ((cg ^ (r0 & 7)) * 8));                 \
      ka1[kd] = *(const bf16x8*)(Kb + r1 * 64 + ((cg ^ (r1 & 7)) * 8));                 \
    }                                                                                   \
    __builtin_amdgcn_s_setprio(1);                                                      \
    _Pragma("unroll") for (int kd = 0; kd < 4; ++kd) {                                  \
      S0 = __builtin_amdgcn_mfma_f32_32x32x16_bf16(ka0[kd], qB[kd], S0, 0, 0, 0);       \
      S1 = __builtin_amdgcn_mfma_f32_32x32x16_bf16(ka1[kd], qB[kd], S1, 0, 0, 0);       \
    }                                                                                   \
    __builtin_amdgcn_s_setprio(0);                                                      \
  }

#define SMPV(S0, S1, T)                                                                 \
  {                                                                                     \
    const u16* Vb = Vl0 + ((T) % 3) * 4096;                                             \
    bf16x8 vf[2][4];                                                                    \
    _Pragma("unroll") for (int dt = 0; dt < 2; ++dt) _Pragma("unroll")                  \
        for (int kt = 0; kt < 4; ++kt) {                                                \
          int r = dt * 32 + ql;                                                         \
          int cg = 2 * kt + Lh;                                                         \
          vf[dt][kt] = *(const bf16x8*)(Vb + r * 64 + ((cg ^ (r & 7)) * 8));            \
        }                                                                               \
    unsigned dw0[8], dw1[8];                                                            \
    float ls0 = 0.f, ls1 = 0.f;                                                         \
    _Pragma("unroll") for (int m = 0; m < 8; ++m) {                                     \
      float p0 = ex2(S0[2 * m]), p1 = ex2(S0[2 * m + 1]);                               \
      float p2 = ex2(S1[2 * m]), p3 = ex2(S1[2 * m + 1]);                               \
      ls0 += p0 + p1; ls1 += p2 + p3;                                                   \
      dw0[m] = cvtpk(p0, p1); dw1[m] = cvtpk(p2, p3);                                   \
    }                                                                                   \
    l_part += ls0 + ls1;                                                                \
    __builtin_amdgcn_s_setprio(1);                                                      \
    _Pragma("unroll") for (int kt = 0; kt < 4; ++kt) {                                  \
      const int c = kt & 1;                                                             \
      unsigned w0, w1, w2, w3;                                                          \
      if (kt < 2) { w0 = dw0[4 * c + 0]; w1 = dw0[4 * c + 2];                           \
                    w2 = dw0[4 * c + 1]; w3 = dw0[4 * c + 3]; }                         \
      else        { w0 = dw1[4 * c + 0]; w1 = dw1[4 * c + 2];                           \
                    w2 = dw1[4 * c + 1]; w3 = dw1[4 * c + 3]; }                         \
      u32x2 s0 = __builtin_amdgcn_permlane32_swap(w0, w1, false, false);                \
      u32x2 s1 = __builtin_amdgcn_permlane32_swap(w2, w3, false, false);                \
      union { unsigned u[4]; bf16x8 v; } pb;                                            \
      pb.u[0] = s0[0]; pb.u[1] = s1[0]; pb.u[2] = s0[1]; pb.u[3] = s1[1];               \
      acco[0] = __builtin_amdgcn_mfma_f32_32x32x16_bf16(vf[0][kt], pb.v, acco[0], 0, 0, 0); \
      acco[1] = __builtin_amdgcn_mfma_f32_32x32x16_bf16(vf[1][kt], pb.v, acco[1], 0, 0, 0); \
    }                                                                                   \
    __builtin_amdgcn_s_setprio(0);                                                      \
  }

  // prologue: stage tiles 0,1 ; drain tile0 (cross-wave via barrier) ; QK(0) -> A
  STAGE(0) STAGE(1)
  asm volatile("s_waitcnt vmcnt(4)" ::: "memory");
  asm volatile("s_barrier" ::: "memory");
  QK(sA0, sA1, 0)

#pragma unroll 1
  for (int it = 0; it < 32; it += 2) {
    PRE(it)                     // drains tile it+1; stages tile it+2 into buf (it+2)%3
    QK(sB0, sB1, it + 1)
    SMPV(sA0, sA1, it)
    PRE(it + 1)                 // drains tile it+2; stages tile it+3
    if (it + 2 < 32) QK(sA0, sA1, it + 2)
    SMPV(sB0, sB1, it + 1)
  }
#undef STAGE
#undef PRE
#undef QK
#undef SMPV

  // epilogue: O[q][d], d = 32dt + 8g + 4Lh + (reg&3)
  float lsum = l_part + __shfl_xor(l_part, 32);
  float inv = 1.f / lsum;
  u16* orow = ao + (size_t)(b * 2048 + qg) * 1024 + h * 64;
#pragma unroll
  for (int dt = 0; dt < 2; ++dt)
#pragma unroll
    for (int g = 0; g < 4; ++g) {
      float o0 = acco[dt][4 * g + 0] * inv, o1 = acco[dt][4 * g + 1] * inv;
      float o2 = acco[dt][4 * g + 2] * inv, o3 = acco[dt][4 * g + 3] * inv;
      uint2 w; w.x = cvtpk(o0, o1); w.y = cvtpk(o2, o3);
      *(uint2*)(orow + dt * 32 + g * 8 + Lh * 4) = w;
    }
}

// ---------------- launch ----------------
extern "C" void kernel_launch(void* const* d_in, const int* in_sizes, int n_in,
                              void* d_out, int out_size, void* d_ws, size_t ws_size,
                              hipStream_t stream) {
  const float* x  = (const float*)d_in[0];
  const float* Wq = (const float*)d_in[1];
  const float* bq = (const float*)d_in[2];
  const float* Wk = (const float*)d_in[3];
  const float* bk = (const float*)d_in[4];
  const float* Wv = (const float*)d_in[5];
  const float* bv = (const float*)d_in[6];
  const float* Wo = (const float*)d_in[7];
  const float* bo = (const float*)d_in[8];
  float* out = (float*)d_out;

  char* ws = (char*)d_ws;
  u16* xb    = (u16*)(ws);                       // 8 MB  x bf16 [4096][1024]
  u16* wqkvt = (u16*)(ws + (8u << 20));          // 6 MB  [3072][1024]
  u16* wot   = (u16*)(ws + (14u << 20));         // 2 MB  [1024][1024]
  u16* qk    = (u16*)(ws + (16u << 20));         // 16 MB [4096][2048]
  u16* vt    = (u16*)(ws + (32u << 20));         // 8 MB  [2*16*64][2048]
  u16* aob   = (u16*)(ws + (40u << 20));         // 8 MB  [4096][1024]   (48 MB total)

  k_prep<<<5120, 256, 0, stream>>>(x, Wq, Wk, Wv, Wo, xb, wqkvt, wot);
  k_gemm<0><<<768, 256, 0, stream>>>(xb, wqkvt, bq, bk, bv, qk, vt, nullptr);
  k_attn<<<512, 256, 0, stream>>>(qk, vt, aob);
  k_gemm<2><<<256, 256, 0, stream>>>(aob, wot, bo, nullptr, nullptr, nullptr, nullptr, out);
}